// Round 18
// baseline (210.443 us; speedup 1.0000x reference)
//
#include <hip/hip_runtime.h>
#include <hip/hip_fp16.h>

// QuantizedLinearWhisper: E2M1 block-32 fake-quant of x and W, then x_q @ W_q^T + bias.
// M=12000 (pad 12032=47*256), K=1280, N=5120. Outputs: out[12000][5120] f32, scale_w[5120][40] f32.
//
// R18: full lag-1 pipeline at K32 granularity. 256x256 tile, BK=32 (40 K-tiles),
// 4 LDS buffers (rotation period 4, 32KB each = 128KB), 8 waves 2x4, 1 block/CU.
// Per tile: {vmcnt(4); BAR; stage buf[(t+3)&3] <- tile t+3 (4 glds);
//            read tile t+1 frags into idle set (12 ds_read, NO consumer this tile);
//            32 MFMA on resident set}.
// MFMA cluster has zero same-tile read deps -> reads+stages drain under MFMA.
// Dual frag sets = 96 VGPR peak (register-feasible, unlike K64 lag-1 which spilled).
// Counted vmcnt(4) per tile (publishes t+1; queue = stage(t+1),stage(t+2)).
// Quant: fused single launch (R16/R17 win). Identity block mapping (R16: XCD swizzle hurt).

typedef _Float16 f16;
typedef _Float16 f16x8 __attribute__((ext_vector_type(8)));
typedef float f32x4 __attribute__((ext_vector_type(4)));

#define M_ROWS 12000
#define M_PAD  12032
#define N_COLS 5120
#define K_DIM  1280
#define KB     40
#define NTN    20          // N tiles of 256
#define XBLK   7520        // quant_x blocks: 12032*160/256

#define BAR()   asm volatile("s_barrier" ::: "memory")
#define VMCNT(N) asm volatile("s_waitcnt vmcnt(%0)" :: "i"(N) : "memory")
#define GLDS(gp, lp) __builtin_amdgcn_global_load_lds( \
    (const __attribute__((address_space(1))) unsigned*)(gp), \
    (__attribute__((address_space(3))) unsigned*)(lp), 16, 0, 0)

// ---- E2M1 nearest-level (strict > boundaries, identical to reference) ----
__device__ __forceinline__ float e2m1_level(float a) {
    float lv;
    if (a > 2.5f)       lv = (a > 3.5f) ? ((a > 5.0f) ? 6.0f : 4.0f) : 3.0f;
    else if (a > 1.25f) lv = (a > 1.75f) ? 2.0f : 1.5f;
    else                lv = (a > 0.75f) ? 1.0f : ((a > 0.25f) ? 0.5f : 0.0f);
    return lv;
}

// Fused quantization: blocks [0,XBLK) quantize x -> xq (padded); rest quantize w -> wq + scales.
__global__ __launch_bounds__(256) void quant_fused(const float* __restrict__ x,
                                                   f16* __restrict__ xq,
                                                   const float* __restrict__ w,
                                                   f16* __restrict__ wq,
                                                   float* __restrict__ scale_out) {
    int b = blockIdx.x;
    if (b < XBLK) {
        int t = b * 256 + threadIdx.x;
        int row = t / 160;
        int c8  = t % 160;
        f16x8 o;
        if (row < M_ROWS) {
            const float* p = x + (size_t)row * K_DIM + c8 * 8;
            float v[8];
            *(float4*)&v[0] = *(const float4*)p;
            *(float4*)&v[4] = *(const float4*)(p + 4);
            float am = 0.0f;
            #pragma unroll
            for (int i = 0; i < 8; ++i) am = fmaxf(am, fabsf(v[i]));
            am = fmaxf(am, __shfl_xor(am, 1));
            am = fmaxf(am, __shfl_xor(am, 2));
            float scale = fmaxf(am / 6.0f, 1e-12f);
            #pragma unroll
            for (int i = 0; i < 8; ++i) {
                float tq = v[i] / scale;
                float q  = copysignf(e2m1_level(fabsf(tq)), tq) * scale;
                o[i] = (f16)q;
            }
        } else {
            #pragma unroll
            for (int i = 0; i < 8; ++i) o[i] = (f16)0.0f;
        }
        *(f16x8*)(xq + (size_t)row * K_DIM + c8 * 8) = o;
    } else {
        int t = (b - XBLK) * 256 + threadIdx.x;
        int row = t / 160;
        int c8  = t % 160;
        const float* p = w + (size_t)row * K_DIM + c8 * 8;
        float v[8];
        *(float4*)&v[0] = *(const float4*)p;
        *(float4*)&v[4] = *(const float4*)(p + 4);
        float am = 0.0f;
        #pragma unroll
        for (int i = 0; i < 8; ++i) am = fmaxf(am, fabsf(v[i]));
        am = fmaxf(am, __shfl_xor(am, 1));
        am = fmaxf(am, __shfl_xor(am, 2));
        float scale = fmaxf(am / 6.0f, 1e-12f);
        if ((t & 3) == 0) scale_out[row * KB + (c8 >> 2)] = scale;
        f16x8 o;
        #pragma unroll
        for (int i = 0; i < 8; ++i) {
            float tq = v[i] / scale;
            float q  = copysignf(e2m1_level(fabsf(tq)), tq) * scale;
            o[i] = (f16)q;
        }
        *(f16x8*)(wq + (size_t)row * K_DIM + c8 * 8) = o;
    }
}

// ---- GEMM 256x256, BK=32, 8 waves 2x4 (wave tile 128x64), 4-buffer rotation ----
// Buffer k (32KB): A[256 rows][4 chunks 16B] at sm + k*16384 (f16), B same at +8192.
// Chunk c of row r stored at slot (c ^ ((r>>1)&3)) [R8-proven conflict-free for 64B rows];
// staging pre-swizzles the global source chunk; LDS dest linear.

__device__ __forceinline__ void stage32(const f16* __restrict__ g, f16* l, int tid) {
    #pragma unroll
    for (int s = 0; s < 2; ++s) {
        int j = s * 512 + tid;          // 1024 chunks (256 rows x 4)
        int r = j >> 2;
        int c = (j & 3) ^ ((r >> 1) & 3);
        GLDS(g + (size_t)r * K_DIM + c * 8, l + (size_t)j * 8);
    }
}

// One K32-tile. RA/RB: buffer holding tile t+1 (read into ar/br, idle set).
// SA/SB: stage target buf[(t+3)&3]. am/bm: resident set (tile t) -> 32 MFMA.
// VM: 4 steady, 0 at t=38, -1 none (t=39).
template<int VM, bool STG, bool RD>
__device__ __forceinline__ void kt(const f16* RA, const f16* RB,
                                   f16* SA, f16* SB,
                                   const f16* gA3, const f16* gB3,
                                   f16x8 (&ar)[8], f16x8 (&br)[4],
                                   const f16x8 (&am)[8], const f16x8 (&bm)[4],
                                   f32x4 (&acc)[8][4],
                                   int tid, int arow0, int brow0, int swzc) {
    if (VM == 4) VMCNT(4);
    else if (VM == 0) VMCNT(0);
    BAR();
    if (STG) { stage32(gA3, SA, tid); stage32(gB3, SB, tid); }
    if (RD) {
        #pragma unroll
        for (int fm = 0; fm < 8; ++fm)
            ar[fm] = *(const f16x8*)&RA[(arow0 + fm * 16) * 32 + swzc];
        #pragma unroll
        for (int fn = 0; fn < 4; ++fn)
            br[fn] = *(const f16x8*)&RB[(brow0 + fn * 16) * 32 + swzc];
    }
    __builtin_amdgcn_s_setprio(1);
    #pragma unroll
    for (int fm = 0; fm < 8; ++fm)
        #pragma unroll
        for (int fn = 0; fn < 4; ++fn)
            acc[fm][fn] = __builtin_amdgcn_mfma_f32_16x16x32_f16(am[fm], bm[fn], acc[fm][fn], 0, 0, 0);
    __builtin_amdgcn_s_setprio(0);
}

__global__ __launch_bounds__(512, 2) void gemm_kernel(const f16* __restrict__ A,
                                                      const f16* __restrict__ B,
                                                      const float* __restrict__ bias,
                                                      float* __restrict__ C) {
    extern __shared__ f16 sm[];            // 4 bufs x 16384 f16 = 128 KiB
    int mt = blockIdx.x / NTN;             // identity mapping (R16: XCD swizzle hurt)
    int nt = blockIdx.x % NTN;

    int tid  = threadIdx.x;
    int lane = tid & 63;
    int wid  = tid >> 6;
    int wr   = wid >> 2;                   // 0..1
    int wc   = wid & 3;                    // 0..3
    int l15  = lane & 15;

    // swizzled chunk offset for 64B rows: g ^ ((row>>1)&3); row low bits == l15
    int swzc  = (((lane >> 4) ^ ((l15 >> 1) & 3)) << 3);
    int arow0 = wr * 128 + l15;
    int brow0 = wc * 64 + l15;

    const f16* gAb = A + (size_t)(mt * 256) * K_DIM;
    const f16* gBb = B + (size_t)(nt * 256) * K_DIM;

    f16* A0 = sm;              f16* B0 = sm + 8192;
    f16* A1 = sm + 16384;      f16* B1 = sm + 24576;
    f16* A2 = sm + 32768;      f16* B2 = sm + 40960;
    f16* A3 = sm + 49152;      f16* B3 = sm + 57344;

    f32x4 acc[8][4] = {};
    f16x8 a0[8], b0[4], a1[8], b1[4];      // dual fragment sets (static names, rule #20)

    // prologue: stage tiles 0,1,2 -> bufs 0,1,2 (12 glds); vmcnt(8) drains tile0;
    // read tile0 frags into set0.
    stage32(gAb,      A0, tid); stage32(gBb,      B0, tid);
    stage32(gAb + 32, A1, tid); stage32(gBb + 32, B1, tid);
    stage32(gAb + 64, A2, tid); stage32(gBb + 64, B2, tid);
    VMCNT(8);
    BAR();
    #pragma unroll
    for (int fm = 0; fm < 8; ++fm)
        a0[fm] = *(const f16x8*)&A0[(arow0 + fm * 16) * 32 + swzc];
    #pragma unroll
    for (int fn = 0; fn < 4; ++fn)
        b0[fn] = *(const f16x8*)&B0[(brow0 + fn * 16) * 32 + swzc];

    // main loop: tiles 0..35 (9 x 4-tile unroll), then explicit 36..39.
    // tile t: read buf[(t+1)&3] -> set[(t+1)&1]; stage buf[(t+3)&3] <- tile t+3;
    //         MFMA on set[t&1]; vmcnt(4) publishes t+1.
    for (int it = 0; it < 9; ++it) {
        int t = 4 * it;
        kt<4, true, true>(A1, B1, A3, B3, gAb + (t + 3) * 32, gBb + (t + 3) * 32,
                          a1, b1, a0, b0, acc, tid, arow0, brow0, swzc);   // t
        kt<4, true, true>(A2, B2, A0, B0, gAb + (t + 4) * 32, gBb + (t + 4) * 32,
                          a0, b0, a1, b1, acc, tid, arow0, brow0, swzc);   // t+1
        kt<4, true, true>(A3, B3, A1, B1, gAb + (t + 5) * 32, gBb + (t + 5) * 32,
                          a1, b1, a0, b0, acc, tid, arow0, brow0, swzc);   // t+2
        kt<4, true, true>(A0, B0, A2, B2, gAb + (t + 6) * 32, gBb + (t + 6) * 32,
                          a0, b0, a1, b1, acc, tid, arow0, brow0, swzc);   // t+3
    }
    kt<4, true, true>(A1, B1, A3, B3, gAb + 39 * 32, gBb + 39 * 32,
                      a1, b1, a0, b0, acc, tid, arow0, brow0, swzc);       // t=36
    kt<4, false, true>(A2, B2, A2, B2, gAb, gBb,
                       a0, b0, a1, b1, acc, tid, arow0, brow0, swzc);      // t=37
    kt<0, false, true>(A3, B3, A3, B3, gAb, gBb,
                       a1, b1, a0, b0, acc, tid, arow0, brow0, swzc);      // t=38
    kt<-1, false, false>(A0, B0, A0, B0, gAb, gBb,
                         a0, b0, a1, b1, acc, tid, arow0, brow0, swzc);    // t=39

    // ---- epilogue: C = acc + bias.  C/D layout: col=lane&15, row=(lane>>4)*4+j
    int crow0 = mt * 256 + wr * 128;
    int ccol  = nt * 256 + wc * 64 + l15;
    float bz[4];
    #pragma unroll
    for (int fn = 0; fn < 4; ++fn) bz[fn] = bias[ccol + fn * 16];

    #pragma unroll
    for (int fm = 0; fm < 8; ++fm) {
        #pragma unroll
        for (int j = 0; j < 4; ++j) {
            int row = crow0 + fm * 16 + (lane >> 4) * 4 + j;
            if (row < M_ROWS) {
                float* cp = C + (size_t)row * N_COLS + ccol;
                #pragma unroll
                for (int fn = 0; fn < 4; ++fn)
                    cp[fn * 16] = acc[fm][fn][j] + bz[fn];
            }
        }
    }
}

extern "C" void kernel_launch(void* const* d_in, const int* in_sizes, int n_in,
                              void* d_out, int out_size, void* d_ws, size_t ws_size,
                              hipStream_t stream) {
    const float* x      = (const float*)d_in[0];
    const float* weight = (const float*)d_in[1];
    const float* bias   = (const float*)d_in[2];
    float* out     = (float*)d_out;
    float* scale_w = (float*)d_out + (size_t)M_ROWS * N_COLS;

    f16* xq = (f16*)d_ws;
    f16* wq = (f16*)((char*)d_ws + (size_t)M_PAD * K_DIM * sizeof(f16));

    (void)hipFuncSetAttribute((const void*)gemm_kernel,
                              hipFuncAttributeMaxDynamicSharedMemorySize, 131072);

    {
        int wblocks = N_COLS * (K_DIM / 8) / 256;    // 3200
        quant_fused<<<XBLK + wblocks, 256, 0, stream>>>(x, xq, weight, wq, scale_w);
    }
    {
        int grid = (M_PAD / 256) * (N_COLS / 256);   // 47 * 20 = 940
        gemm_kernel<<<grid, 512, 131072, stream>>>(xq, wq, bias, out);
    }
}

// Round 19
// 207.630 us; speedup vs baseline: 1.0135x; 1.0135x over previous
//
#include <hip/hip_runtime.h>
#include <hip/hip_fp16.h>

// QuantizedLinearWhisper: E2M1 block-32 fake-quant of x and W, then x_q @ W_q^T + bias.
// M=12000 (pad 12032=47*256), K=1280, N=5120. Outputs: out[12000][5120] f32, scale_w[5120][40] f32.
//
// R19: A-only lag-1 pipeline at K32 granularity (register-feasible fix of R18).
// 256x256 tile, BK=32 (40 K-tiles), 4 LDS buffers (32KB each), 8 waves 2x4, 1 block/CU.
// Per tile: {vmcnt(4); BAR; stage buf[(t+3)&3]; read B(t) FIRST (4 ds, in-order LDS
// returns -> completes before A reads); read A(t+1) into idle set (8 ds, no consumer
// this tile); 32 MFMA on am(resident)*bm}. First MFMA waits only on bm[0]; A reads
// + stage drain under the MFMA cluster. Frag regs: A dual 64 + B 16 = 80 (no spill).
// Counted vmcnt(4)/tile (publishes t+1). Fused quant launch; identity block mapping.

typedef _Float16 f16;
typedef _Float16 f16x8 __attribute__((ext_vector_type(8)));
typedef float f32x4 __attribute__((ext_vector_type(4)));

#define M_ROWS 12000
#define M_PAD  12032
#define N_COLS 5120
#define K_DIM  1280
#define KB     40
#define NTN    20          // N tiles of 256
#define XBLK   7520        // quant_x blocks: 12032*160/256

#define BAR()   asm volatile("s_barrier" ::: "memory")
#define VMCNT(N) asm volatile("s_waitcnt vmcnt(%0)" :: "i"(N) : "memory")
#define GLDS(gp, lp) __builtin_amdgcn_global_load_lds( \
    (const __attribute__((address_space(1))) unsigned*)(gp), \
    (__attribute__((address_space(3))) unsigned*)(lp), 16, 0, 0)

// ---- E2M1 nearest-level (strict > boundaries, identical to reference) ----
__device__ __forceinline__ float e2m1_level(float a) {
    float lv;
    if (a > 2.5f)       lv = (a > 3.5f) ? ((a > 5.0f) ? 6.0f : 4.0f) : 3.0f;
    else if (a > 1.25f) lv = (a > 1.75f) ? 2.0f : 1.5f;
    else                lv = (a > 0.75f) ? 1.0f : ((a > 0.25f) ? 0.5f : 0.0f);
    return lv;
}

// Fused quantization: blocks [0,XBLK) quantize x -> xq (padded); rest quantize w -> wq + scales.
__global__ __launch_bounds__(256) void quant_fused(const float* __restrict__ x,
                                                   f16* __restrict__ xq,
                                                   const float* __restrict__ w,
                                                   f16* __restrict__ wq,
                                                   float* __restrict__ scale_out) {
    int b = blockIdx.x;
    if (b < XBLK) {
        int t = b * 256 + threadIdx.x;
        int row = t / 160;
        int c8  = t % 160;
        f16x8 o;
        if (row < M_ROWS) {
            const float* p = x + (size_t)row * K_DIM + c8 * 8;
            float v[8];
            *(float4*)&v[0] = *(const float4*)p;
            *(float4*)&v[4] = *(const float4*)(p + 4);
            float am = 0.0f;
            #pragma unroll
            for (int i = 0; i < 8; ++i) am = fmaxf(am, fabsf(v[i]));
            am = fmaxf(am, __shfl_xor(am, 1));
            am = fmaxf(am, __shfl_xor(am, 2));
            float scale = fmaxf(am / 6.0f, 1e-12f);
            #pragma unroll
            for (int i = 0; i < 8; ++i) {
                float tq = v[i] / scale;
                float q  = copysignf(e2m1_level(fabsf(tq)), tq) * scale;
                o[i] = (f16)q;
            }
        } else {
            #pragma unroll
            for (int i = 0; i < 8; ++i) o[i] = (f16)0.0f;
        }
        *(f16x8*)(xq + (size_t)row * K_DIM + c8 * 8) = o;
    } else {
        int t = (b - XBLK) * 256 + threadIdx.x;
        int row = t / 160;
        int c8  = t % 160;
        const float* p = w + (size_t)row * K_DIM + c8 * 8;
        float v[8];
        *(float4*)&v[0] = *(const float4*)p;
        *(float4*)&v[4] = *(const float4*)(p + 4);
        float am = 0.0f;
        #pragma unroll
        for (int i = 0; i < 8; ++i) am = fmaxf(am, fabsf(v[i]));
        am = fmaxf(am, __shfl_xor(am, 1));
        am = fmaxf(am, __shfl_xor(am, 2));
        float scale = fmaxf(am / 6.0f, 1e-12f);
        if ((t & 3) == 0) scale_out[row * KB + (c8 >> 2)] = scale;
        f16x8 o;
        #pragma unroll
        for (int i = 0; i < 8; ++i) {
            float tq = v[i] / scale;
            float q  = copysignf(e2m1_level(fabsf(tq)), tq) * scale;
            o[i] = (f16)q;
        }
        *(f16x8*)(wq + (size_t)row * K_DIM + c8 * 8) = o;
    }
}

// ---- GEMM 256x256, BK=32, 8 waves 2x4 (wave tile 128x64), 4-buffer rotation ----
// Buffer k (32KB): A[256 rows][4 chunks 16B] at sm + k*16384 (f16), B same at +8192.
// Chunk c of row r at slot (c ^ ((r>>1)&3)) [R8-proven conflict-free for 64B rows];
// staging pre-swizzles the global source chunk; LDS dest linear.

__device__ __forceinline__ void stage32(const f16* __restrict__ g, f16* l, int tid) {
    #pragma unroll
    for (int s = 0; s < 2; ++s) {
        int j = s * 512 + tid;          // 1024 chunks (256 rows x 4)
        int r = j >> 2;
        int c = (j & 3) ^ ((r >> 1) & 3);
        GLDS(g + (size_t)r * K_DIM + c * 8, l + (size_t)j * 8);
    }
}

// One K32-tile. RA: buffer holding A(t+1) (lag read into ar). Bb: buffer of tile t
// (B read same-tile, issued FIRST). SA/SB: stage target buf[(t+3)&3].
// am: resident A set (read last tile). VM: 4 steady, 0 at t=38, -1 none.
template<int VM, bool STG, bool RDA>
__device__ __forceinline__ void kt(const f16* RA, const f16* Bb,
                                   f16* SA, f16* SB,
                                   const f16* gA3, const f16* gB3,
                                   f16x8 (&ar)[8], const f16x8 (&am)[8],
                                   f32x4 (&acc)[8][4],
                                   int tid, int arow0, int brow0, int swzc) {
    if (VM == 4) VMCNT(4);
    else if (VM == 0) VMCNT(0);
    BAR();
    if (STG) { stage32(gA3, SA, tid); stage32(gB3, SB, tid); }
    // B first: in-order LDS returns mean bm completes before the A lag-reads;
    // the first MFMA's lgkm wait covers only bm, never ar.
    f16x8 bm[4];
    #pragma unroll
    for (int fn = 0; fn < 4; ++fn)
        bm[fn] = *(const f16x8*)&Bb[(brow0 + fn * 16) * 32 + swzc];
    if (RDA) {
        #pragma unroll
        for (int fm = 0; fm < 8; ++fm)
            ar[fm] = *(const f16x8*)&RA[(arow0 + fm * 16) * 32 + swzc];
    }
    __builtin_amdgcn_s_setprio(1);
    #pragma unroll
    for (int fn = 0; fn < 4; ++fn)
        #pragma unroll
        for (int fm = 0; fm < 8; ++fm)
            acc[fm][fn] = __builtin_amdgcn_mfma_f32_16x16x32_f16(am[fm], bm[fn], acc[fm][fn], 0, 0, 0);
    __builtin_amdgcn_s_setprio(0);
}

__global__ __launch_bounds__(512, 2) void gemm_kernel(const f16* __restrict__ A,
                                                      const f16* __restrict__ B,
                                                      const float* __restrict__ bias,
                                                      float* __restrict__ C) {
    extern __shared__ f16 sm[];            // 4 bufs x 16384 f16 = 128 KiB
    int mt = blockIdx.x / NTN;             // identity mapping (R16: XCD swizzle hurt)
    int nt = blockIdx.x % NTN;

    int tid  = threadIdx.x;
    int lane = tid & 63;
    int wid  = tid >> 6;
    int wr   = wid >> 2;                   // 0..1
    int wc   = wid & 3;                    // 0..3
    int l15  = lane & 15;

    // swizzled chunk offset for 64B rows: g ^ ((row>>1)&3); row low bits == l15
    int swzc  = (((lane >> 4) ^ ((l15 >> 1) & 3)) << 3);
    int arow0 = wr * 128 + l15;
    int brow0 = wc * 64 + l15;

    const f16* gAb = A + (size_t)(mt * 256) * K_DIM;
    const f16* gBb = B + (size_t)(nt * 256) * K_DIM;

    f16* A0 = sm;              f16* B0 = sm + 8192;
    f16* A1 = sm + 16384;      f16* B1 = sm + 24576;
    f16* A2 = sm + 32768;      f16* B2 = sm + 40960;
    f16* A3 = sm + 49152;      f16* B3 = sm + 57344;

    f32x4 acc[8][4] = {};
    f16x8 a0[8], a1[8];                    // dual A sets (static names, rule #20)

    // prologue: stage tiles 0,1,2 -> bufs 0,1,2 (12 glds); vmcnt(8) drains tile0;
    // read A(0) into set0. (B(0) read inside kt(0).)
    stage32(gAb,      A0, tid); stage32(gBb,      B0, tid);
    stage32(gAb + 32, A1, tid); stage32(gBb + 32, B1, tid);
    stage32(gAb + 64, A2, tid); stage32(gBb + 64, B2, tid);
    VMCNT(8);
    BAR();
    #pragma unroll
    for (int fm = 0; fm < 8; ++fm)
        a0[fm] = *(const f16x8*)&A0[(arow0 + fm * 16) * 32 + swzc];

    // main loop: t=0..35 (9 x 4-tile unroll); tile t: B from buf[t&3], A(t+1) from
    // buf[(t+1)&3] into set[(t+1)&1], stage buf[(t+3)&3] <- tile t+3, MFMA set[t&1].
    for (int it = 0; it < 9; ++it) {
        int t = 4 * it;
        kt<4, true, true>(A1, B0, A3, B3, gAb + (t + 3) * 32, gBb + (t + 3) * 32,
                          a1, a0, acc, tid, arow0, brow0, swzc);   // t
        kt<4, true, true>(A2, B1, A0, B0, gAb + (t + 4) * 32, gBb + (t + 4) * 32,
                          a0, a1, acc, tid, arow0, brow0, swzc);   // t+1
        kt<4, true, true>(A3, B2, A1, B1, gAb + (t + 5) * 32, gBb + (t + 5) * 32,
                          a1, a0, acc, tid, arow0, brow0, swzc);   // t+2
        kt<4, true, true>(A0, B3, A2, B2, gAb + (t + 6) * 32, gBb + (t + 6) * 32,
                          a0, a1, acc, tid, arow0, brow0, swzc);   // t+3
    }
    kt<4, true, true>(A1, B0, A3, B3, gAb + 39 * 32, gBb + 39 * 32,
                      a1, a0, acc, tid, arow0, brow0, swzc);       // t=36 (stages 39)
    kt<4, false, true>(A2, B1, A2, B2, gAb, gBb,
                       a0, a1, acc, tid, arow0, brow0, swzc);      // t=37
    kt<0, false, true>(A3, B2, A3, B3, gAb, gBb,
                       a1, a0, acc, tid, arow0, brow0, swzc);      // t=38
    kt<-1, false, false>(A0, B3, A0, B0, gAb, gBb,
                         a0, a1, acc, tid, arow0, brow0, swzc);    // t=39

    // ---- epilogue: C = acc + bias.  C/D layout: col=lane&15, row=(lane>>4)*4+j
    int crow0 = mt * 256 + wr * 128;
    int ccol  = nt * 256 + wc * 64 + l15;
    float bz[4];
    #pragma unroll
    for (int fn = 0; fn < 4; ++fn) bz[fn] = bias[ccol + fn * 16];

    #pragma unroll
    for (int fm = 0; fm < 8; ++fm) {
        #pragma unroll
        for (int j = 0; j < 4; ++j) {
            int row = crow0 + fm * 16 + (lane >> 4) * 4 + j;
            if (row < M_ROWS) {
                float* cp = C + (size_t)row * N_COLS + ccol;
                #pragma unroll
                for (int fn = 0; fn < 4; ++fn)
                    cp[fn * 16] = acc[fm][fn][j] + bz[fn];
            }
        }
    }
}

extern "C" void kernel_launch(void* const* d_in, const int* in_sizes, int n_in,
                              void* d_out, int out_size, void* d_ws, size_t ws_size,
                              hipStream_t stream) {
    const float* x      = (const float*)d_in[0];
    const float* weight = (const float*)d_in[1];
    const float* bias   = (const float*)d_in[2];
    float* out     = (float*)d_out;
    float* scale_w = (float*)d_out + (size_t)M_ROWS * N_COLS;

    f16* xq = (f16*)d_ws;
    f16* wq = (f16*)((char*)d_ws + (size_t)M_PAD * K_DIM * sizeof(f16));

    (void)hipFuncSetAttribute((const void*)gemm_kernel,
                              hipFuncAttributeMaxDynamicSharedMemorySize, 131072);

    {
        int wblocks = N_COLS * (K_DIM / 8) / 256;    // 3200
        quant_fused<<<XBLK + wblocks, 256, 0, stream>>>(x, xq, weight, wq, scale_w);
    }
    {
        int grid = (M_PAD / 256) * (N_COLS / 256);   // 47 * 20 = 940
        gemm_kernel<<<grid, 512, 131072, stream>>>(xq, wq, bias, out);
    }
}

// Round 20
// 190.378 us; speedup vs baseline: 1.1054x; 1.0906x over previous
//
#include <hip/hip_runtime.h>
#include <hip/hip_fp16.h>

// QuantizedLinearWhisper: E2M1 block-32 fake-quant of x and W, then x_q @ W_q^T + bias.
// M=12000 (pad 12032=47*256), K=1280, N=5120. Outputs: out[12000][5120] f32, scale_w[5120][40] f32.
//
// FINAL (R20 = R17, best measured: total 189.8us, GEMM 167us / 944 TF / MfmaUtil 42.5%,
// zero spill, zero bank conflicts, absmax 0.039).
// - Quant: fused single launch, bit-exact fp32 reference op order, fp16 storage.
// - GEMM: 256x256, BK=64, 8 waves (2x4), 1 block/CU, 8-phase schedule
//   {stage 1 half-tile; ds-read this phase's operands; MFMA 16; BAR}, counted vmcnt(4)
//   publishes only at phases 4/8, raw s_barrier, setprio on MFMA, XOR chunk swizzle.
// - Identity block mapping (XCD swizzle measured -4% on this L3-fit shape).
// Structural plateau: schedules fitting 128 arch-VGPRs serialize LDS vs MFMA pipes
// (~42% MfmaUtil); decoupling them needs >128 live regs -> spill (measured 5x).

typedef _Float16 f16;
typedef _Float16 f16x8 __attribute__((ext_vector_type(8)));
typedef float f32x4 __attribute__((ext_vector_type(4)));

#define M_ROWS 12000
#define M_PAD  12032
#define N_COLS 5120
#define K_DIM  1280
#define KB     40
#define NTN    20          // N tiles of 256
#define XBLK   7520        // quant_x blocks: 12032*160/256

#define BAR()   asm volatile("s_barrier" ::: "memory")
#define VMCNT(N) asm volatile("s_waitcnt vmcnt(%0)" :: "i"(N) : "memory")
#define GLDS(gp, lp) __builtin_amdgcn_global_load_lds( \
    (const __attribute__((address_space(1))) unsigned*)(gp), \
    (__attribute__((address_space(3))) unsigned*)(lp), 16, 0, 0)

// ---- E2M1 nearest-level (strict > boundaries, identical to reference) ----
__device__ __forceinline__ float e2m1_level(float a) {
    float lv;
    if (a > 2.5f)       lv = (a > 3.5f) ? ((a > 5.0f) ? 6.0f : 4.0f) : 3.0f;
    else if (a > 1.25f) lv = (a > 1.75f) ? 2.0f : 1.5f;
    else                lv = (a > 0.75f) ? 1.0f : ((a > 0.25f) ? 0.5f : 0.0f);
    return lv;
}

// Fused quantization: blocks [0,XBLK) quantize x -> xq (padded); rest quantize w -> wq + scales.
__global__ __launch_bounds__(256) void quant_fused(const float* __restrict__ x,
                                                   f16* __restrict__ xq,
                                                   const float* __restrict__ w,
                                                   f16* __restrict__ wq,
                                                   float* __restrict__ scale_out) {
    int b = blockIdx.x;
    if (b < XBLK) {
        int t = b * 256 + threadIdx.x;
        int row = t / 160;
        int c8  = t % 160;
        f16x8 o;
        if (row < M_ROWS) {
            const float* p = x + (size_t)row * K_DIM + c8 * 8;
            float v[8];
            *(float4*)&v[0] = *(const float4*)p;
            *(float4*)&v[4] = *(const float4*)(p + 4);
            float am = 0.0f;
            #pragma unroll
            for (int i = 0; i < 8; ++i) am = fmaxf(am, fabsf(v[i]));
            am = fmaxf(am, __shfl_xor(am, 1));
            am = fmaxf(am, __shfl_xor(am, 2));
            float scale = fmaxf(am / 6.0f, 1e-12f);
            #pragma unroll
            for (int i = 0; i < 8; ++i) {
                float tq = v[i] / scale;
                float q  = copysignf(e2m1_level(fabsf(tq)), tq) * scale;
                o[i] = (f16)q;
            }
        } else {
            #pragma unroll
            for (int i = 0; i < 8; ++i) o[i] = (f16)0.0f;
        }
        *(f16x8*)(xq + (size_t)row * K_DIM + c8 * 8) = o;
    } else {
        int t = (b - XBLK) * 256 + threadIdx.x;
        int row = t / 160;
        int c8  = t % 160;
        const float* p = w + (size_t)row * K_DIM + c8 * 8;
        float v[8];
        *(float4*)&v[0] = *(const float4*)p;
        *(float4*)&v[4] = *(const float4*)(p + 4);
        float am = 0.0f;
        #pragma unroll
        for (int i = 0; i < 8; ++i) am = fmaxf(am, fabsf(v[i]));
        am = fmaxf(am, __shfl_xor(am, 1));
        am = fmaxf(am, __shfl_xor(am, 2));
        float scale = fmaxf(am / 6.0f, 1e-12f);
        if ((t & 3) == 0) scale_out[row * KB + (c8 >> 2)] = scale;
        f16x8 o;
        #pragma unroll
        for (int i = 0; i < 8; ++i) {
            float tq = v[i] / scale;
            float q  = copysignf(e2m1_level(fabsf(tq)), tq) * scale;
            o[i] = (f16)q;
        }
        *(f16x8*)(wq + (size_t)row * K_DIM + c8 * 8) = o;
    }
}

// ---- GEMM 256x256, BK=64, 8 waves 2x4, per-wave 128x64 out ----
// LDS per tile-buffer: A [256 rows][8 chunks of 16B] (32KB) + B same; chunk c of row r
// at slot (c ^ (r&7)); stage pre-swizzles the global source chunk. 128 KiB total.

__device__ __forceinline__ void stage_half(const f16* __restrict__ g, f16* l, int tid) {
    #pragma unroll
    for (int s = 0; s < 2; ++s) {
        int j = s * 512 + tid;          // chunk 0..1023 (128 rows x 8 chunks)
        int r = j >> 3;
        int c = (j & 7) ^ (r & 7);
        GLDS(g + (size_t)r * K_DIM + c * 8, l + (size_t)j * 8);
    }
}

#define READ_A(dst, buf, rbase)                                                \
    _Pragma("unroll")                                                          \
    for (int fm = 0; fm < 4; ++fm) {                                           \
        dst[fm][0] = *(const f16x8*)&(buf)[((rbase) + fm * 16) * 64 + swz[0]]; \
        dst[fm][1] = *(const f16x8*)&(buf)[((rbase) + fm * 16) * 64 + swz[1]]; \
    }
#define READ_B(dst, buf, rbase)                                                \
    _Pragma("unroll")                                                          \
    for (int fn = 0; fn < 2; ++fn) {                                           \
        dst[fn][0] = *(const f16x8*)&(buf)[((rbase) + fn * 16) * 64 + swz[0]]; \
        dst[fn][1] = *(const f16x8*)&(buf)[((rbase) + fn * 16) * 64 + swz[1]]; \
    }
#define MFMA_Q(ma, mb, mo, no)                                                 \
    __builtin_amdgcn_s_setprio(1);                                             \
    _Pragma("unroll")                                                          \
    for (int fm = 0; fm < 4; ++fm)                                             \
        _Pragma("unroll")                                                      \
        for (int fn = 0; fn < 2; ++fn) {                                       \
            acc[fm + mo][fn + no] = __builtin_amdgcn_mfma_f32_16x16x32_f16(    \
                ma[fm][0], mb[fn][0], acc[fm + mo][fn + no], 0, 0, 0);         \
            acc[fm + mo][fn + no] = __builtin_amdgcn_mfma_f32_16x16x32_f16(    \
                ma[fm][1], mb[fn][1], acc[fm + mo][fn + no], 0, 0, 0);         \
        }                                                                      \
    __builtin_amdgcn_s_setprio(0);

// One iteration = tiles 2i (buf0) and 2i+1 (buf1), stages per slot table.
// SREST gates slots F3..F8 (tiles 2i+2, 2i+3); V4 = vmcnt at end of F4.
template<bool SREST, int V4>
__device__ __forceinline__ void iter8(f16* A0, f16* B0, f16* A1, f16* B1,
                                      const f16* gA1, const f16* gA2,
                                      const f16* gB2, const f16* gB3,
                                      f32x4 (&acc)[8][4],
                                      int tid, int arow0, int brow0, const int (&swz)[2]) {
    f16x8 aLO[4][2], aHI[4][2], bLO[2][2], bHI[2][2];

    // ---- F1: stage A(2i+1).lo -> buf1; read aLO+bLO (tile 2i); Q1
    stage_half(gA1, A1, tid);
    READ_A(aLO, A0, arow0);
    READ_B(bLO, B0, brow0);
    MFMA_Q(aLO, bLO, 0, 0);
    BAR();
    // ---- F2: stage A(2i+1).hi; read bHI; Q2
    stage_half(gA1 + 128 * K_DIM, A1 + 8192, tid);
    READ_B(bHI, B0, brow0 + 32);
    MFMA_Q(aLO, bHI, 0, 2);
    BAR();
    // ---- F3: stage B(2i+2).lo -> buf0 (B0 reads done F2); read aHI; Q3
    if (SREST) stage_half(gB2, B0, tid);
    READ_A(aHI, A0, arow0 + 64);
    MFMA_Q(aHI, bHI, 4, 2);
    BAR();
    // ---- F4: stage A(2i+2).lo -> buf0 (A0 reads done F3); Q4; publish tile 2i+1
    if (SREST) stage_half(gA2, A0, tid);
    MFMA_Q(aHI, bLO, 4, 0);
    VMCNT(V4);
    BAR();
    // ---- F5: stage A(2i+2).hi; read aLO+bLO (tile 2i+1); Q1
    if (SREST) stage_half(gA2 + 128 * K_DIM, A0 + 8192, tid);
    READ_A(aLO, A1, arow0);
    READ_B(bLO, B1, brow0);
    MFMA_Q(aLO, bLO, 0, 0);
    BAR();
    // ---- F6: stage B(2i+2).hi; read bHI; Q2
    if (SREST) stage_half(gB2 + 128 * K_DIM, B0 + 8192, tid);
    READ_B(bHI, B1, brow0 + 32);
    MFMA_Q(aLO, bHI, 0, 2);
    BAR();
    // ---- F7: stage B(2i+3).lo -> buf1 (B1 reads done F6); read aHI; Q3
    if (SREST) stage_half(gB3, B1, tid);
    READ_A(aHI, A1, arow0 + 64);
    MFMA_Q(aHI, bHI, 4, 2);
    BAR();
    // ---- F8: stage B(2i+3).hi; Q4; publish tile 2i+2
    if (SREST) stage_half(gB3 + 128 * K_DIM, B1 + 8192, tid);
    MFMA_Q(aHI, bLO, 4, 0);
    if (SREST) VMCNT(4);
    BAR();
}

__global__ __launch_bounds__(512, 2) void gemm_kernel(const f16* __restrict__ A,
                                                      const f16* __restrict__ B,
                                                      const float* __restrict__ bias,
                                                      float* __restrict__ C) {
    extern __shared__ f16 sm[];            // 2 tile-bufs x (A 16384 + B 16384 f16) = 128 KiB
    int mt = blockIdx.x / NTN;             // identity mapping (XCD swizzle hurt on this shape)
    int nt = blockIdx.x % NTN;

    int tid  = threadIdx.x;
    int lane = tid & 63;
    int wid  = tid >> 6;
    int wr   = wid >> 2;                   // 0..1
    int wc   = wid & 3;                    // 0..3
    int l15  = lane & 15;

    int swz[2] = { (((lane >> 4)    ) ^ (lane & 7)) * 8,
                   (((lane >> 4) + 4) ^ (lane & 7)) * 8 };
    int arow0 = wr * 128 + l15;
    int brow0 = wc * 64 + l15;

    const f16* gAb = A + (size_t)(mt * 256) * K_DIM;
    const f16* gBb = B + (size_t)(nt * 256) * K_DIM;

    f16* A0 = sm;
    f16* B0 = sm + 16384;
    f16* A1 = sm + 32768;
    f16* B1 = sm + 49152;

    f32x4 acc[8][4] = {};

    // prologue: stage tile0 fully + tile1's B (slot order B0lo,A0lo,A0hi,B0hi,B1lo,B1hi);
    // vmcnt(4) publishes tile0; B1 stays in flight (drained at F4(0)'s vmcnt(4)).
    stage_half(gBb,               B0,        tid);
    stage_half(gAb,               A0,        tid);
    stage_half(gAb + 128 * K_DIM, A0 + 8192, tid);
    stage_half(gBb + 128 * K_DIM, B0 + 8192, tid);
    stage_half(gBb + 64,               B1,        tid);
    stage_half(gBb + 64 + 128 * K_DIM, B1 + 8192, tid);
    VMCNT(4);
    BAR();

    for (int i = 0; i < 9; ++i) {
        const f16* gA1 = gAb + (2 * i + 1) * 64;
        const f16* gA2 = gAb + (2 * i + 2) * 64;
        const f16* gB2 = gBb + (2 * i + 2) * 64;
        const f16* gB3 = gBb + (2 * i + 3) * 64;
        iter8<true, 4>(A0, B0, A1, B1, gA1, gA2, gB2, gB3,
                       acc, tid, arow0, brow0, swz);
    }
    // last iteration (tiles 18,19): stage only A19 (F1/F2); publish with vmcnt(0)
    iter8<false, 0>(A0, B0, A1, B1, gAb + 19 * 64, gAb, gBb, gBb,
                    acc, tid, arow0, brow0, swz);

    // ---- epilogue: C = acc + bias.  C/D layout: col=lane&15, row=(lane>>4)*4+j
    int crow0 = mt * 256 + wr * 128;
    int ccol  = nt * 256 + wc * 64 + l15;
    float bz[4];
    #pragma unroll
    for (int fn = 0; fn < 4; ++fn) bz[fn] = bias[ccol + fn * 16];

    #pragma unroll
    for (int fm = 0; fm < 8; ++fm) {
        #pragma unroll
        for (int j = 0; j < 4; ++j) {
            int row = crow0 + fm * 16 + (lane >> 4) * 4 + j;
            if (row < M_ROWS) {
                float* cp = C + (size_t)row * N_COLS + ccol;
                #pragma unroll
                for (int fn = 0; fn < 4; ++fn)
                    cp[fn * 16] = acc[fm][fn][j] + bz[fn];
            }
        }
    }
}

extern "C" void kernel_launch(void* const* d_in, const int* in_sizes, int n_in,
                              void* d_out, int out_size, void* d_ws, size_t ws_size,
                              hipStream_t stream) {
    const float* x      = (const float*)d_in[0];
    const float* weight = (const float*)d_in[1];
    const float* bias   = (const float*)d_in[2];
    float* out     = (float*)d_out;
    float* scale_w = (float*)d_out + (size_t)M_ROWS * N_COLS;

    f16* xq = (f16*)d_ws;
    f16* wq = (f16*)((char*)d_ws + (size_t)M_PAD * K_DIM * sizeof(f16));

    (void)hipFuncSetAttribute((const void*)gemm_kernel,
                              hipFuncAttributeMaxDynamicSharedMemorySize, 131072);

    {
        int wblocks = N_COLS * (K_DIM / 8) / 256;    // 3200
        quant_fused<<<XBLK + wblocks, 256, 0, stream>>>(x, xq, weight, wq, scale_w);
    }
    {
        int grid = (M_PAD / 256) * (N_COLS / 256);   // 47 * 20 = 940
        gemm_kernel<<<grid, 512, 131072, stream>>>(xq, wq, bias, out);
    }
}